// Round 5
// baseline (574.727 us; speedup 1.0000x reference)
//
#include <hip/hip_runtime.h>
#include <math.h>

#define BATCH 2
#define TSTEPS 8

typedef __attribute__((ext_vector_type(8))) short s16x8;   // 8 bf16 (4 VGPRs)
typedef __attribute__((ext_vector_type(4))) float f32x4;   // MFMA accum

__device__ __forceinline__ float hsig(float v){ return fminf(fmaxf(0.2f*v+0.5f,0.f),1.f); }

__device__ __forceinline__ ushort f2bf(float f){
    uint u = __builtin_bit_cast(uint, f);
    u = (u + 0x7FFFu + ((u >> 16) & 1u)) >> 16;   // round-to-nearest-even
    return (ushort)u;
}

__global__ void cast_bf16_kernel(const float* __restrict__ src, ushort* __restrict__ dst, int n){
    int i = blockIdx.x * 256 + threadIdx.x;
    if (i < n) dst[i] = f2bf(src[i]);
}

// W [K][N] fp32 -> Wt [N][K] bf16. interleave: dst row n' = co*4+g pulls src col g*Co+co.
__global__ void transw_kernel(const float* __restrict__ W, ushort* __restrict__ Wt,
                              int K, int N, int Co, int interleave){
    int i = blockIdx.x * 256 + threadIdx.x;
    if (i >= K * N) return;
    int n = i / K, k = i - n * K;
    int ns = n;
    if (interleave){ int g = n & 3, co = n >> 2; ns = g * Co + co; }
    Wt[i] = f2bf(W[(size_t)k * N + ns]);
}

// ---------------------------------------------------------------------------
// convx: implicit-im2col GEMM, bf16 MFMA. Tile 128x128, BK=32, 256 thr.
// Depth-2 prefetch, triple-buffered LDS, one barrier per K-iter.
// ---------------------------------------------------------------------------
__global__ __launch_bounds__(256) void convx_mfma(
    const ushort* __restrict__ Abf, const ushort* __restrict__ Wt,
    const float* __restrict__ bias, float* __restrict__ Zx,
    int H, int Wd, int Ci, int N, int K)
{
    __shared__ char smem[3 * 20480];   // per buf: As 128x40 bf16 (10240 B) + Bs (10240 B)

    const int tid = threadIdx.x;
    const int m0 = blockIdx.x * 128, n0 = blockIdx.y * 128;
    const int lane = tid & 63, wave = tid >> 6;
    const int wm = wave >> 1, wn = wave & 1;
    const int quad = lane >> 4, l16 = lane & 15;

    const int r2 = tid >> 1;            // 0..127 : A row and B row
    const int ko = (tid & 1) << 3;      // 0/8 ; second chunk at +16
    const int HW = H * Wd;
    const int p = m0 + r2;
    const int bt = p / HW; const int rem = p - bt * HW;
    const int y = rem / Wd, x = rem - (rem / Wd) * Wd;
    const ushort* browx = &Wt[(size_t)(n0 + r2) * K + ko];

    char* pb0 = smem;            // consume (tile it)
    char* pb1 = smem + 20480;    // store target (tile it+1)
    char* pb2 = smem + 40960;

    const int iters = K / 32;
    int kN = 0, tapN = 0, ciN = 0;      // next tile to load (uniform scalars)

    uint4 a0B, a1B, b0B, b1B;           // regs holding tile it+1

    // ---- prologue: tile 0 -> pb0 ----
    {
        const int kh = tapN / 3, kw = tapN - (tapN / 3) * 3;
        const int yy = y + kh - 1, xx = x + kw - 1;
        uint4 a0 = make_uint4(0,0,0,0), a1 = make_uint4(0,0,0,0);
        if (yy >= 0 && yy < H && xx >= 0 && xx < Wd){
            const ushort* ap = &Abf[((size_t)(bt * H + yy) * Wd + xx) * Ci + ciN + ko];
            a0 = *(const uint4*)ap; a1 = *(const uint4*)(ap + 16);
        }
        uint4 b0 = *(const uint4*)&browx[kN];
        uint4 b1 = *(const uint4*)&browx[kN + 16];
        ushort* As = (ushort*)pb0; ushort* Bs = (ushort*)(pb0 + 10240);
        *(uint4*)&As[r2 * 40 + ko] = a0; *(uint4*)&As[r2 * 40 + ko + 16] = a1;
        *(uint4*)&Bs[r2 * 40 + ko] = b0; *(uint4*)&Bs[r2 * 40 + ko + 16] = b1;
        kN += 32; ciN += 32; if (ciN == Ci){ ciN = 0; ++tapN; }
    }
    // ---- prologue: tile 1 -> regsB ----
    {
        const int kh = tapN / 3, kw = tapN - (tapN / 3) * 3;
        const int yy = y + kh - 1, xx = x + kw - 1;
        a0B = make_uint4(0,0,0,0); a1B = make_uint4(0,0,0,0);
        if (yy >= 0 && yy < H && xx >= 0 && xx < Wd){
            const ushort* ap = &Abf[((size_t)(bt * H + yy) * Wd + xx) * Ci + ciN + ko];
            a0B = *(const uint4*)ap; a1B = *(const uint4*)(ap + 16);
        }
        b0B = *(const uint4*)&browx[kN];
        b1B = *(const uint4*)&browx[kN + 16];
        kN += 32; ciN += 32; if (ciN == Ci){ ciN = 0; ++tapN; }
    }
    __syncthreads();

    f32x4 acc[4][4] = {};

    for (int it = 0; it < iters; ++it){
        // issue loads for tile it+2
        uint4 a0A = make_uint4(0,0,0,0), a1A = make_uint4(0,0,0,0);
        uint4 b0A = make_uint4(0,0,0,0), b1A = make_uint4(0,0,0,0);
        if (it + 2 < iters){
            const int kh = tapN / 3, kw = tapN - (tapN / 3) * 3;
            const int yy = y + kh - 1, xx = x + kw - 1;
            if (yy >= 0 && yy < H && xx >= 0 && xx < Wd){
                const ushort* ap = &Abf[((size_t)(bt * H + yy) * Wd + xx) * Ci + ciN + ko];
                a0A = *(const uint4*)ap; a1A = *(const uint4*)(ap + 16);
            }
            b0A = *(const uint4*)&browx[kN];
            b1A = *(const uint4*)&browx[kN + 16];
            kN += 32; ciN += 32; if (ciN == Ci){ ciN = 0; ++tapN; }
        }
        // store tile it+1 (regsB) into pb1
        if (it + 1 < iters){
            ushort* As = (ushort*)pb1; ushort* Bs = (ushort*)(pb1 + 10240);
            *(uint4*)&As[r2 * 40 + ko] = a0B; *(uint4*)&As[r2 * 40 + ko + 16] = a1B;
            *(uint4*)&Bs[r2 * 40 + ko] = b0B; *(uint4*)&Bs[r2 * 40 + ko + 16] = b1B;
        }
        // MFMA on tile it (pb0)
        {
            const ushort* As = (const ushort*)pb0;
            const ushort* Bs = (const ushort*)(pb0 + 10240);
            s16x8 af[4], bfr[4];
            #pragma unroll
            for (int mt = 0; mt < 4; ++mt)
                af[mt] = *(const s16x8*)&As[(wm * 64 + mt * 16 + l16) * 40 + quad * 8];
            #pragma unroll
            for (int nt = 0; nt < 4; ++nt)
                bfr[nt] = *(const s16x8*)&Bs[(wn * 64 + nt * 16 + l16) * 40 + quad * 8];
            #pragma unroll
            for (int mt = 0; mt < 4; ++mt)
                #pragma unroll
                for (int nt = 0; nt < 4; ++nt)
                    acc[mt][nt] = __builtin_amdgcn_mfma_f32_16x16x32_bf16(af[mt], bfr[nt], acc[mt][nt], 0, 0, 0);
        }
        __syncthreads();
        a0B = a0A; a1B = a1A; b0B = b0A; b1B = b1A;
        char* tmp = pb0; pb0 = pb1; pb1 = pb2; pb2 = tmp;
    }

    #pragma unroll
    for (int mt = 0; mt < 4; ++mt){
        #pragma unroll
        for (int nt = 0; nt < 4; ++nt){
            const int col = n0 + wn * 64 + nt * 16 + l16;
            const float bv = bias[col];
            #pragma unroll
            for (int r = 0; r < 4; ++r){
                const int row = m0 + wm * 64 + mt * 16 + quad * 4 + r;
                Zx[(size_t)row * N + col] = acc[mt][nt][r] + bv;
            }
        }
    }
}

// ---------------------------------------------------------------------------
// LSTM step: z = Zx[t] + conv(h_prev, Wh), bf16 MFMA, tile 64x64, BK=32.
// Same depth-2 / triple-buffer / one-barrier pipeline.
// Wht gate-interleaved [n'=co*4+g][K]. Epilogue via LDS.
// ---------------------------------------------------------------------------
template<int OUT_BF16>
__global__ __launch_bounds__(256) void step_mfma(
    const float* __restrict__ Zx, const ushort* __restrict__ Wht,
    const ushort* __restrict__ hprev, ushort* __restrict__ hnew,
    float* __restrict__ cst,
    const float* __restrict__ gamma, const float* __restrict__ beta,
    const float* __restrict__ mmean, const float* __restrict__ mvar,
    void* __restrict__ outp, int H, int Wd, int Co, int t)
{
    __shared__ char smem[3 * 10240];   // per buf: As 64x40 (5120 B) + Bs (5120 B); Zs(17408B) aliases

    const int tid = threadIdx.x;
    const int m0 = blockIdx.x * 64, n0 = blockIdx.y * 64;
    const int lane = tid & 63, wave = tid >> 6;
    const int wm = wave >> 1, wn = wave & 1;
    const int quad = lane >> 4, l16 = lane & 15;
    const int N4 = 4 * Co, K = 9 * Co;
    const int HW = H * Wd;

    const int arow = tid >> 2, aq = (tid & 3) << 3;   // 64 rows x 4 chunks of 8 bf16
    const int p = m0 + arow;
    const int b = p / HW; const int rem = p - b * HW;
    const int y = rem / Wd, x = rem - (rem / Wd) * Wd;
    const ushort* brow = &Wht[(size_t)(n0 + arow) * K + aq];

    char* pb0 = smem;
    char* pb1 = smem + 10240;
    char* pb2 = smem + 20480;

    const int iters = K / 32;
    int kN = 0, tapN = 0, ciN = 0;

    uint4 avB, bvB;

    // prologue: tile 0 -> pb0
    {
        const int kh = tapN / 3, kw = tapN - (tapN / 3) * 3;
        const int yy = y + kh - 1, xx = x + kw - 1;
        uint4 av = make_uint4(0,0,0,0);
        if (yy >= 0 && yy < H && xx >= 0 && xx < Wd)
            av = *(const uint4*)&hprev[((size_t)(b * H + yy) * Wd + xx) * Co + ciN + aq];
        uint4 bv = *(const uint4*)&brow[kN];
        *(uint4*)((ushort*)pb0 + arow * 40 + aq) = av;
        *(uint4*)((ushort*)(pb0 + 5120) + arow * 40 + aq) = bv;
        kN += 32; ciN += 32; if (ciN == Co){ ciN = 0; ++tapN; }
    }
    // prologue: tile 1 -> regsB
    {
        const int kh = tapN / 3, kw = tapN - (tapN / 3) * 3;
        const int yy = y + kh - 1, xx = x + kw - 1;
        avB = make_uint4(0,0,0,0);
        if (yy >= 0 && yy < H && xx >= 0 && xx < Wd)
            avB = *(const uint4*)&hprev[((size_t)(b * H + yy) * Wd + xx) * Co + ciN + aq];
        bvB = *(const uint4*)&brow[kN];
        kN += 32; ciN += 32; if (ciN == Co){ ciN = 0; ++tapN; }
    }
    __syncthreads();

    f32x4 acc[2][2] = {};

    for (int it = 0; it < iters; ++it){
        uint4 avA = make_uint4(0,0,0,0), bvA = make_uint4(0,0,0,0);
        if (it + 2 < iters){
            const int kh = tapN / 3, kw = tapN - (tapN / 3) * 3;
            const int yy = y + kh - 1, xx = x + kw - 1;
            if (yy >= 0 && yy < H && xx >= 0 && xx < Wd)
                avA = *(const uint4*)&hprev[((size_t)(b * H + yy) * Wd + xx) * Co + ciN + aq];
            bvA = *(const uint4*)&brow[kN];
            kN += 32; ciN += 32; if (ciN == Co){ ciN = 0; ++tapN; }
        }
        if (it + 1 < iters){
            *(uint4*)((ushort*)pb1 + arow * 40 + aq) = avB;
            *(uint4*)((ushort*)(pb1 + 5120) + arow * 40 + aq) = bvB;
        }
        {
            const ushort* As = (const ushort*)pb0;
            const ushort* Bs = (const ushort*)(pb0 + 5120);
            s16x8 af[2], bfr[2];
            #pragma unroll
            for (int mt = 0; mt < 2; ++mt)
                af[mt] = *(const s16x8*)&As[(wm * 32 + mt * 16 + l16) * 40 + quad * 8];
            #pragma unroll
            for (int nt = 0; nt < 2; ++nt)
                bfr[nt] = *(const s16x8*)&Bs[(wn * 32 + nt * 16 + l16) * 40 + quad * 8];
            #pragma unroll
            for (int mt = 0; mt < 2; ++mt)
                #pragma unroll
                for (int nt = 0; nt < 2; ++nt)
                    acc[mt][nt] = __builtin_amdgcn_mfma_f32_16x16x32_bf16(af[mt], bfr[nt], acc[mt][nt], 0, 0, 0);
        }
        __syncthreads();
        avB = avA; bvB = bvA;
        char* tmp = pb0; pb0 = pb1; pb1 = pb2; pb2 = tmp;
    }

    // stash z tile in LDS (layout [pixel][co*4+g])
    float* Zs = (float*)smem;
    #pragma unroll
    for (int mt = 0; mt < 2; ++mt)
        #pragma unroll
        for (int nt = 0; nt < 2; ++nt)
            #pragma unroll
            for (int r = 0; r < 4; ++r)
                Zs[(wm * 32 + mt * 16 + quad * 4 + r) * 68 + wn * 32 + nt * 16 + l16] = acc[mt][nt][r];
    __syncthreads();

    const int co0 = n0 >> 2;
    #pragma unroll
    for (int it = 0; it < 4; ++it){
        const int idx = it * 256 + tid;
        const int pp = idx >> 4, lco = idx & 15;
        const int m = m0 + pp;
        const int b2 = m / HW; const int rr = m - b2 * HW;
        const int y2 = rr / Wd, x2 = rr - (rr / Wd) * Wd;
        const int co = co0 + lco;

        const float* zrowp = &Zx[((size_t)(b2 * TSTEPS + t) * HW + rr) * N4];
        const float zi = Zs[pp * 68 + lco * 4 + 0] + zrowp[co];
        const float zf = Zs[pp * 68 + lco * 4 + 1] + zrowp[Co + co];
        const float zg = Zs[pp * 68 + lco * 4 + 2] + zrowp[2 * Co + co];
        const float zo = Zs[pp * 68 + lco * 4 + 3] + zrowp[3 * Co + co];

        const float iv = hsig(zi), fv = hsig(zf);
        const float gv = tanhf(zg), ov = hsig(zo);
        const float cold = cst[(size_t)m * Co + co];
        const float cn = fv * cold + iv * gv;
        cst[(size_t)m * Co + co] = cn;
        const float h = ov * tanhf(cn);
        hnew[(size_t)m * Co + co] = f2bf(h);

        const float bnv = (h - mmean[co]) * rsqrtf(mvar[co] + 1e-3f) * gamma[co] + beta[co];
        const int W2 = 2 * Wd;
        const size_t ob = ((size_t)(b2 * TSTEPS + t) * 2 * H + 2 * y2) * W2 + 2 * x2;
        if (OUT_BF16){
            ushort* o = (ushort*)outp; const ushort hv = f2bf(bnv);
            o[ob * Co + co] = hv; o[(ob + 1) * Co + co] = hv;
            o[(ob + W2) * Co + co] = hv; o[(ob + W2 + 1) * Co + co] = hv;
        } else {
            float* o = (float*)outp;
            o[ob * Co + co] = bnv; o[(ob + 1) * Co + co] = bnv;
            o[(ob + W2) * Co + co] = bnv; o[(ob + W2 + 1) * Co + co] = bnv;
        }
    }
}

static void run_block(const ushort* xbf, const ushort* Wxt, const ushort* Wht, const float* bias,
                      const float* g, const float* be, const float* mm, const float* mv,
                      float* Zx, ushort* hA, ushort* hB, float* cbuf, void* out, int out_bf16,
                      int Ci, int Co, int H, int W, hipStream_t stream)
{
    const int N = 4 * Co, K = 9 * Ci;
    const int M = BATCH * TSTEPS * H * W;
    dim3 gx(M / 128, N / 128);
    convx_mfma<<<gx, 256, 0, stream>>>(xbf, Wxt, bias, Zx, H, W, Ci, N, K);

    hipMemsetAsync(hA, 0, (size_t)BATCH * H * W * Co * sizeof(ushort), stream);
    hipMemsetAsync(cbuf, 0, (size_t)BATCH * H * W * Co * sizeof(float), stream);

    const int Ms = BATCH * H * W;
    dim3 gs(Ms / 64, N / 64);
    for (int t = 0; t < TSTEPS; ++t){
        const ushort* hp = (t & 1) ? hB : hA;
        ushort* hn = (t & 1) ? hA : hB;
        if (out_bf16)
            step_mfma<1><<<gs, 256, 0, stream>>>(Zx, Wht, hp, hn, cbuf, g, be, mm, mv, out, H, W, Co, t);
        else
            step_mfma<0><<<gs, 256, 0, stream>>>(Zx, Wht, hp, hn, cbuf, g, be, mm, mv, out, H, W, Co, t);
    }
}

extern "C" void kernel_launch(void* const* d_in, const int* in_sizes, int n_in,
                              void* d_out, int out_size, void* d_ws, size_t ws_size,
                              hipStream_t stream) {
    const float* x   = (const float*)d_in[0];
    const float* Wx1 = (const float*)d_in[1];  const float* Wh1 = (const float*)d_in[2];
    const float* b1  = (const float*)d_in[3];  const float* g1  = (const float*)d_in[4];
    const float* be1 = (const float*)d_in[5];  const float* mm1 = (const float*)d_in[6];
    const float* mv1 = (const float*)d_in[7];
    const float* Wx2 = (const float*)d_in[8];  const float* Wh2 = (const float*)d_in[9];
    const float* b2  = (const float*)d_in[10]; const float* g2  = (const float*)d_in[11];
    const float* be2 = (const float*)d_in[12]; const float* mm2 = (const float*)d_in[13];
    const float* mv2 = (const float*)d_in[14];
    const float* Wx3 = (const float*)d_in[15]; const float* Wh3 = (const float*)d_in[16];
    const float* b3  = (const float*)d_in[17]; const float* g3  = (const float*)d_in[18];
    const float* be3 = (const float*)d_in[19]; const float* mm3 = (const float*)d_in[20];
    const float* mv3 = (const float*)d_in[21];

    char* ws = (char*)d_ws;
    size_t off = 0;
    auto alloc = [&](size_t bytes) { char* p = ws + off; off += (bytes + 255) & ~(size_t)255; return p; };

    float*  Zx   = (float*)alloc(8388608ull * 4);      // max Zx (block3: 65536*128)
    float*  cbuf = (float*)alloc(262144ull * 4);       // max c (block3: 8192*32)
    ushort* xbf  = (ushort*)alloc(786432ull * 2);      // x cast
    ushort* x2   = (ushort*)alloc(2097152ull * 2);     // block1 out (bf16)
    ushort* x3   = (ushort*)alloc(4194304ull * 2);     // block2 out (bf16)
    ushort* hA   = (ushort*)alloc(262144ull * 2);
    ushort* hB   = (ushort*)alloc(262144ull * 2);
    ushort* Wxt1 = (ushort*)alloc(884736ull * 2);
    ushort* Wxt2 = (ushort*)alloc(294912ull * 2);
    ushort* Wxt3 = (ushort*)alloc(73728ull * 2);
    ushort* Wht1 = (ushort*)alloc(589824ull * 2);
    ushort* Wht2 = (ushort*)alloc(147456ull * 2);
    ushort* Wht3 = (ushort*)alloc(36864ull * 2);

    // prep: casts + weight transposes
    cast_bf16_kernel<<<(786432 + 255) / 256, 256, 0, stream>>>(x, xbf, 786432);
    transw_kernel<<<(884736 + 255) / 256, 256, 0, stream>>>(Wx1, Wxt1, 1728, 512, 128, 0);
    transw_kernel<<<(294912 + 255) / 256, 256, 0, stream>>>(Wx2, Wxt2, 1152, 256, 64, 0);
    transw_kernel<<<(73728  + 255) / 256, 256, 0, stream>>>(Wx3, Wxt3,  576, 128, 32, 0);
    transw_kernel<<<(589824 + 255) / 256, 256, 0, stream>>>(Wh1, Wht1, 1152, 512, 128, 1);
    transw_kernel<<<(147456 + 255) / 256, 256, 0, stream>>>(Wh2, Wht2,  576, 256, 64, 1);
    transw_kernel<<<(36864  + 255) / 256, 256, 0, stream>>>(Wh3, Wht3,  288, 128, 32, 1);

    run_block(xbf, Wxt1, Wht1, b1, g1, be1, mm1, mv1, Zx, hA, hB, cbuf, x2, 1, 192, 128, 16, 16, stream);
    run_block(x2,  Wxt2, Wht2, b2, g2, be2, mm2, mv2, Zx, hA, hB, cbuf, x3, 1, 128,  64, 32, 32, stream);
    run_block(x3,  Wxt3, Wht3, b3, g3, be3, mm3, mv3, Zx, hA, hB, cbuf, d_out, 0, 64, 32, 64, 64, stream);
}